// Round 4
// baseline (1451.318 us; speedup 1.0000x reference)
//
#include <hip/hip_runtime.h>

#define NN 60000
#define NE 300000

static inline int cdiv(int a, int b) { return (a + b - 1) / b; }

__device__ inline unsigned ord_enc(float x) {
  unsigned u = __float_as_uint(x);
  return (u & 0x80000000u) ? ~u : (u | 0x80000000u);
}
__device__ inline float ord_dec(unsigned u) {
  return __uint_as_float((u & 0x80000000u) ? (u & 0x7fffffffu) : ~u);
}

// ---------------- fold: precompute folded weight products (7424 dots of length 64) -------
__global__ void fold_kernel(const float* __restrict__ fp_w, const float* __restrict__ fp_b,
                            const float* __restrict__ ep_w, const float* __restrict__ ep_b,
                            const float* __restrict__ fij, const float* __restrict__ ebias,
                            const float* __restrict__ ni, const float* __restrict__ nj,
                            const float* __restrict__ node, float* __restrict__ fold) {
  int t = blockIdx.x * blockDim.x + threadIdx.x;
  if (t >= 7424) return;
  int o = t & 63;
  const float* A;
  const float* B;
  float init = 0.f;
  if (t < 1024)      { A = ep_w + (size_t)(t >> 6) * 64; B = fij + o; }
  else if (t < 1088) { A = ep_b; B = fij + o; init = ebias[o]; }
  else if (t < 3136) { A = fp_w + (size_t)((t - 1088) >> 6) * 64; B = ni + o; }
  else if (t < 5184) { A = fp_w + (size_t)((t - 3136) >> 6) * 64; B = nj + o; }
  else if (t < 7232) { A = fp_w + (size_t)((t - 5184) >> 6) * 64; B = node + o; }
  else if (t < 7296) { A = fp_b; B = ni + o; }
  else if (t < 7360) { A = fp_b; B = nj + o; }
  else               { A = fp_b; B = node + o; }
  float a = init;
  for (int i = 0; i < 64; ++i) a = fmaf(A[i], B[(size_t)i * 64], a);
  fold[t] = a;
}

// ---------------- matvec via shfl-broadcast, 4-row ILP ----------------
// out[r][o] = b[o] + sum_i x[r][i]*W[i][o]; lane=o, W column in regs, x per-lane coalesced.
template <int IN, bool BIAS>
__global__ __launch_bounds__(256, 4) void matvec_kernel(const float* __restrict__ x,
                                                        const float* __restrict__ W,
                                                        const float* __restrict__ b,
                                                        float* __restrict__ out, int rows) {
  int lane = threadIdx.x & 63;
  float w[IN];
#pragma unroll
  for (int i = 0; i < IN; ++i) w[i] = W[(size_t)i * 64 + lane];
  float bv = BIAS ? b[lane] : 0.f;
  int wave = (blockIdx.x * blockDim.x + threadIdx.x) >> 6;
  int nw = (gridDim.x * blockDim.x) >> 6;
  int ngroups = rows >> 2;  // rows divisible by 4 (60000)
  for (int g = wave; g < ngroups; g += nw) {
    int r = g * 4;
    float x0 = (lane < IN) ? x[(size_t)(r + 0) * IN + lane] : 0.f;
    float x1 = (lane < IN) ? x[(size_t)(r + 1) * IN + lane] : 0.f;
    float x2 = (lane < IN) ? x[(size_t)(r + 2) * IN + lane] : 0.f;
    float x3 = (lane < IN) ? x[(size_t)(r + 3) * IN + lane] : 0.f;
    float a0 = bv, a1 = bv, a2 = bv, a3 = bv;
#pragma unroll
    for (int i = 0; i < IN; ++i) {
      a0 = fmaf(__shfl(x0, i, 64), w[i], a0);
      a1 = fmaf(__shfl(x1, i, 64), w[i], a1);
      a2 = fmaf(__shfl(x2, i, 64), w[i], a2);
      a3 = fmaf(__shfl(x3, i, 64), w[i], a3);
    }
    out[(size_t)(r + 0) * 64 + lane] = a0;
    out[(size_t)(r + 1) * 64 + lane] = a1;
    out[(size_t)(r + 2) * 64 + lane] = a2;
    out[(size_t)(r + 3) * 64 + lane] = a3;
  }
}

// ---------------- EGAT: per-edge f_out + attention logit (shfl-broadcast, 2-edge ILP) ----
template <int KW, bool STORE>
__global__ __launch_bounds__(256, 4) void fout_kernel(
    const float* __restrict__ fin, const float* __restrict__ hs, const float* __restrict__ hd,
    const int* __restrict__ src, const int* __restrict__ dst, const float* __restrict__ W,
    const float* __restrict__ attn, const float* __restrict__ bias, float* __restrict__ fstore,
    float* __restrict__ logit, unsigned* __restrict__ nmax) {
  int lane = threadIdx.x & 63;
  float w[KW];
#pragma unroll
  for (int i = 0; i < KW; ++i) w[i] = W[(size_t)i * 64 + lane];
  float bv = bias[lane], av = attn[lane];
  int wave = (blockIdx.x * blockDim.x + threadIdx.x) >> 6;
  int nw = (gridDim.x * blockDim.x) >> 6;
  for (int g = wave; g < NE / 2; g += nw) {
    int e0 = g * 2, e1 = g * 2 + 1;
    int s0 = src[e0], d0 = dst[e0];
    int s1 = src[e1], d1 = dst[e1];
    float f0 = (lane < KW) ? fin[(size_t)e0 * KW + lane] : 0.f;
    float f1 = (lane < KW) ? fin[(size_t)e1 * KW + lane] : 0.f;
    float a0 = hs[(size_t)s0 * 64 + lane] + hd[(size_t)d0 * 64 + lane] + bv;
    float a1 = hs[(size_t)s1 * 64 + lane] + hd[(size_t)d1 * 64 + lane] + bv;
#pragma unroll
    for (int i = 0; i < KW; ++i) {
      a0 = fmaf(__shfl(f0, i, 64), w[i], a0);
      a1 = fmaf(__shfl(f1, i, 64), w[i], a1);
    }
    float o0 = a0 >= 0.f ? a0 : 0.01f * a0;  // LeakyReLU
    float o1 = a1 >= 0.f ? a1 : 0.01f * a1;
    if (STORE) {
      fstore[(size_t)e0 * 64 + lane] = o0;
      fstore[(size_t)e1 * 64 + lane] = o1;
    }
    float p0 = o0 * av, p1 = o1 * av;
#pragma unroll
    for (int off = 32; off; off >>= 1) {
      p0 += __shfl_xor(p0, off, 64);
      p1 += __shfl_xor(p1, off, 64);
    }
    if (lane == 0) {
      logit[e0] = p0;
      atomicMax(nmax + d0, ord_enc(p0));
      logit[e1] = p1;
      atomicMax(nmax + d1, ord_enc(p1));
    }
  }
}

// ---------------- EGAT: edge softmax numerator + segment denom ----------------
__global__ void expsum_kernel(const float* __restrict__ logit, const int* __restrict__ dst,
                              const unsigned* __restrict__ nmax, float* __restrict__ wbuf,
                              float* __restrict__ nsum) {
  int e = blockIdx.x * blockDim.x + threadIdx.x;
  if (e >= NE) return;
  int d = dst[e];
  float m = ord_dec(nmax[d]);
  float w = __expf(logit[e] - m);
  wbuf[e] = w;
  atomicAdd(nsum + d, w);
}

// ---------------- EGAT: scatter-aggregate (softmax normalization fused) ----------------
__global__ void aggregate_kernel(const float* __restrict__ hn, const int* __restrict__ src,
                                 const int* __restrict__ dst, const float* __restrict__ wbuf,
                                 const float* __restrict__ nsum, float* __restrict__ hnew) {
  int idx = blockIdx.x * blockDim.x + threadIdx.x;
  if (idx >= NE * 64) return;
  int e = idx >> 6, o = idx & 63;
  int d = dst[e];
  float a = wbuf[e] / nsum[d];
  float v = hn[(size_t)src[e] * 64 + o] * a;
  atomicAdd(hnew + (size_t)d * 64 + o, v);
}

// ---------------- NNConv stage 1: per-node z = face @ nn_w, q = face @ nn_b --------------
#define ZCHUNK 128
__global__ void zq_kernel(const float* __restrict__ face, const float* __restrict__ nn_w,
                          const float* __restrict__ nn_b, float* __restrict__ z,
                          float* __restrict__ q) {
  __shared__ float s_x[ZCHUNK * 32];
  int tid = threadIdx.x;
  int c = blockIdx.y * 256 + tid;  // 0..767, active < 544
  float w[32];
  float* outp = z;
  int stride = 512;
  if (c < 512) {
    int o = c >> 4, k = c & 15;
#pragma unroll
    for (int i = 0; i < 32; ++i) w[i] = nn_w[(size_t)k * 1024 + i * 32 + o];
    outp = z + c;
  } else if (c < 544) {
    int o = c - 512;
#pragma unroll
    for (int i = 0; i < 32; ++i) w[i] = nn_b[(size_t)i * 32 + o];
    outp = q + o;
    stride = 32;
  }
  int nbase = blockIdx.x * ZCHUNK;
  int ncnt = min(ZCHUNK, NN - nbase);
  for (int j = tid; j < ncnt * 32; j += 256) s_x[j] = face[(size_t)nbase * 32 + j];
  __syncthreads();
  if (c >= 544) return;
  for (int nl = 0; nl < ncnt; ++nl) {
    const float4* xr = (const float4*)(s_x + nl * 32);
    float acc = 0.f;
#pragma unroll
    for (int j = 0; j < 8; ++j) {
      float4 xv = xr[j];
      acc = fmaf(xv.x, w[j * 4 + 0], acc);
      acc = fmaf(xv.y, w[j * 4 + 1], acc);
      acc = fmaf(xv.z, w[j * 4 + 2], acc);
      acc = fmaf(xv.w, w[j * 4 + 3], acc);
    }
    outp[(size_t)(nbase + nl) * stride] = acc;
  }
}

// ---------------- NNConv stage 2: per-edge m[e][o] = q[s][o] + sum_k ef[e][k]*z[s][o*16+k]
__global__ void nnconv_edge_kernel(const float* __restrict__ z, const float* __restrict__ q,
                                   const float* __restrict__ ef, const int* __restrict__ src,
                                   const int* __restrict__ dst, float* __restrict__ sArr,
                                   float* __restrict__ cnt) {
  int gid = blockIdx.x * blockDim.x + threadIdx.x;
  if (gid >= NE * 32) return;
  int e = gid >> 5, o = gid & 31;
  int s = src[e], d = dst[e];
  const float4* zr = (const float4*)(z + (size_t)s * 512 + o * 16);
  const float4* er = (const float4*)(ef + (size_t)e * 16);
  float acc = q[(size_t)s * 32 + o];
#pragma unroll
  for (int j = 0; j < 4; ++j) {
    float4 zv = zr[j], ev = er[j];
    acc = fmaf(ev.x, zv.x, acc);
    acc = fmaf(ev.y, zv.y, acc);
    acc = fmaf(ev.z, zv.z, acc);
    acc = fmaf(ev.w, zv.w, acc);
  }
  atomicAdd(sArr + (size_t)d * 32 + o, acc);
  if (o == 0) atomicAdd(cnt + d, 1.0f);
}

// ---------------- combine into node_features ----------------
__global__ void combine_kernel(const float* __restrict__ hfin, const float* __restrict__ sArr,
                               const float* __restrict__ cnt, const float* __restrict__ nn_bias,
                               float* __restrict__ out) {
  int idx = blockIdx.x * blockDim.x + threadIdx.x;
  if (idx >= NN * 128) return;
  int n = idx >> 7, c = idx & 127;
  float v;
  if (c < 64) v = hfin[(size_t)n * 64 + c];
  else if (c < 96) v = sArr[(size_t)n * 32 + (c - 64)] / fmaxf(cnt[n], 1.0f) + nn_bias[c - 64];
  else v = 0.f;
  out[idx] = v;
}

// ---------------- global attention pooling ----------------
__global__ void gate_logit_kernel(const float* __restrict__ nf, const float* __restrict__ gate_w,
                                  const float* __restrict__ gate_b, float* __restrict__ g,
                                  unsigned* __restrict__ gmax) {
  int n = blockIdx.x * blockDim.x + threadIdx.x;
  float v = -3.0e38f;
  if (n < NN) {
    float acc = gate_b[0];
    const float* r = nf + (size_t)n * 128;
#pragma unroll
    for (int c = 0; c < 96; ++c) acc = fmaf(r[c], gate_w[c], acc);  // cols 96..127 are zero
    g[n] = acc;
    v = acc;
  }
#pragma unroll
  for (int off = 32; off; off >>= 1) v = fmaxf(v, __shfl_xor(v, off, 64));
  __shared__ float sm[4];
  int lane = threadIdx.x & 63, wid = threadIdx.x >> 6;
  if (lane == 0) sm[wid] = v;
  __syncthreads();
  if (threadIdx.x == 0) {
    float m = fmaxf(fmaxf(sm[0], sm[1]), fmaxf(sm[2], sm[3]));
    atomicMax(gmax, ord_enc(m));
  }
}

__global__ void gate_exp_kernel(float* __restrict__ g, const unsigned* __restrict__ gmax,
                                float* __restrict__ gsum) {
  int n = blockIdx.x * blockDim.x + threadIdx.x;
  float m = ord_dec(*gmax);
  float w = 0.f;
  if (n < NN) { w = __expf(g[n] - m); g[n] = w; }
  float v = w;
#pragma unroll
  for (int off = 32; off; off >>= 1) v += __shfl_xor(v, off, 64);
  __shared__ float sm[4];
  int lane = threadIdx.x & 63, wid = threadIdx.x >> 6;
  if (lane == 0) sm[wid] = v;
  __syncthreads();
  if (threadIdx.x == 0) atomicAdd(gsum, sm[0] + sm[1] + sm[2] + sm[3]);
}

__global__ void pool_kernel(const float* __restrict__ nf, const float* __restrict__ gw,
                            float* __restrict__ gacc) {
  int o = threadIdx.x;  // blockDim = 128
  float acc = 0.f;
  for (int n = blockIdx.x; n < NN; n += gridDim.x)
    acc += gw[n] * nf[(size_t)n * 128 + o];
  atomicAdd(gacc + o, acc);
}

__global__ void finalize_kernel(const float* __restrict__ gacc, const float* __restrict__ gsum,
                                float* __restrict__ out) {
  int o = threadIdx.x;
  if (o < 128) out[(size_t)NN * 128 + o] = gacc[o] / gsum[0];
}

extern "C" void kernel_launch(void* const* d_in, const int* in_sizes, int n_in,
                              void* d_out, int out_size, void* d_ws, size_t ws_size,
                              hipStream_t stream) {
  const float* face    = (const float*)d_in[0];
  const float* ef      = (const float*)d_in[1];
  const float* fp_w    = (const float*)d_in[2];
  const float* fp_b    = (const float*)d_in[3];
  const float* ep_w    = (const float*)d_in[4];
  const float* ep_b    = (const float*)d_in[5];
  const float* nn_w    = (const float*)d_in[6];
  const float* nn_b    = (const float*)d_in[7];
  const float* nn_bias = (const float*)d_in[8];
  const float* gate_w  = (const float*)d_in[9];
  const float* gate_b  = (const float*)d_in[10];
  const int*   src     = (const int*)d_in[11];
  const int*   dst     = (const int*)d_in[12];
  const float* e1_attn = (const float*)d_in[17];
  const float* e2_ni   = (const float*)d_in[19];
  const float* e2_nj   = (const float*)d_in[20];
  const float* e2_fij  = (const float*)d_in[21];
  const float* e2_node = (const float*)d_in[22];
  const float* e2_attn = (const float*)d_in[23];
  const float* e2_bias = (const float*)d_in[24];
  float* out = (float*)d_out;

  char* p = (char*)d_ws;
  auto alloc = [&](size_t nfloats) {
    float* r = (float*)p;
    p += ((nfloats * 4 + 255) / 256) * 256;
    return r;
  };
  float* h0 = alloc((size_t)NN * 64);   // layer-2 output
  float* h1 = alloc((size_t)NN * 64);   // layer-1 output; q aliases after EGAT
  char* regionC = p;                    // hs|hd|hn|f1 = 122.88 MB, dead after EGAT
  float* hs    = alloc((size_t)NN * 64);
  float* hd    = alloc((size_t)NN * 64);
  float* hn    = alloc((size_t)NN * 64);
  float* f1    = alloc((size_t)NE * 64);
  float* logit = alloc(NE);
  float* wbuf  = alloc(NE);
  unsigned* nmax = (unsigned*)alloc(NN);
  float* nsum  = alloc(NN);
  float* sArr  = alloc((size_t)NN * 32);
  float* cnt   = alloc(NN);
  float* g     = alloc(NN);
  float* gacc  = alloc(128);
  float* gsum  = alloc(1);
  unsigned* gmax = (unsigned*)alloc(1);
  float* fold  = alloc(7424);
  float* z = (float*)regionC;           // NN*512 floats == hs+hd+hn+f1 region
  float* q = h1;                        // NN*32 <= h1's NN*64, h1 dead post-EGAT

  const float* Wf1  = fold;
  const float* b1f  = fold + 1024;
  const float* Wni1 = fold + 1088;
  const float* Wnj1 = fold + 3136;
  const float* Wno1 = fold + 5184;
  const float* bni1 = fold + 7232;
  const float* bnj1 = fold + 7296;
  const float* bno1 = fold + 7360;

  const int B = 256;

  // folded weights (tiny)
  fold_kernel<<<29, B, 0, stream>>>(fp_w, fp_b, ep_w, ep_b,
                                    (const float*)d_in[15], (const float*)d_in[18],
                                    (const float*)d_in[13], (const float*)d_in[14],
                                    (const float*)d_in[16], fold);

  // ---- EGAT layer 1 (face-level folds: h0/f0 never materialized) ----
  hipMemsetAsync(nmax, 0, NN * 4, stream);
  hipMemsetAsync(nsum, 0, NN * 4, stream);
  hipMemsetAsync(h1, 0, (size_t)NN * 64 * 4, stream);
  matvec_kernel<32, true><<<2048, B, 0, stream>>>(face, Wni1, bni1, hs, NN);
  matvec_kernel<32, true><<<2048, B, 0, stream>>>(face, Wnj1, bnj1, hd, NN);
  matvec_kernel<32, true><<<2048, B, 0, stream>>>(face, Wno1, bno1, hn, NN);
  fout_kernel<16, true><<<2048, B, 0, stream>>>(ef, hs, hd, src, dst, Wf1, e1_attn, b1f,
                                                f1, logit, nmax);
  expsum_kernel<<<cdiv(NE, B), B, 0, stream>>>(logit, dst, nmax, wbuf, nsum);
  aggregate_kernel<<<cdiv(NE * 64, B), B, 0, stream>>>(hn, src, dst, wbuf, nsum, h1);

  // ---- EGAT layer 2 ----
  hipMemsetAsync(nmax, 0, NN * 4, stream);
  hipMemsetAsync(nsum, 0, NN * 4, stream);
  hipMemsetAsync(h0, 0, (size_t)NN * 64 * 4, stream);
  matvec_kernel<64, false><<<2048, B, 0, stream>>>(h1, e2_ni, nullptr, hs, NN);
  matvec_kernel<64, false><<<2048, B, 0, stream>>>(h1, e2_nj, nullptr, hd, NN);
  matvec_kernel<64, false><<<2048, B, 0, stream>>>(h1, e2_node, nullptr, hn, NN);
  fout_kernel<64, false><<<2048, B, 0, stream>>>(f1, hs, hd, src, dst, e2_fij, e2_attn, e2_bias,
                                                 nullptr, logit, nmax);
  expsum_kernel<<<cdiv(NE, B), B, 0, stream>>>(logit, dst, nmax, wbuf, nsum);
  aggregate_kernel<<<cdiv(NE * 64, B), B, 0, stream>>>(hn, src, dst, wbuf, nsum, h0);

  // ---- NNConv (z/q alias dead EGAT buffers — must run after EGAT) ----
  hipMemsetAsync(sArr, 0, (size_t)NN * 32 * 4, stream);
  hipMemsetAsync(cnt, 0, NN * 4, stream);
  {
    dim3 zg(cdiv(NN, ZCHUNK), 3);
    zq_kernel<<<zg, B, 0, stream>>>(face, nn_w, nn_b, z, q);
  }
  nnconv_edge_kernel<<<cdiv(NE * 32, B), B, 0, stream>>>(z, q, ef, src, dst, sArr, cnt);

  // ---- combine node features (Gf | Ef | zeros) ----
  combine_kernel<<<cdiv(NN * 128, B), B, 0, stream>>>(h0, sArr, cnt, nn_bias, out);

  // ---- global attention pooling ----
  hipMemsetAsync(gacc, 0, 128 * 4, stream);
  hipMemsetAsync(gsum, 0, 4, stream);
  hipMemsetAsync(gmax, 0, 4, stream);
  gate_logit_kernel<<<cdiv(NN, B), B, 0, stream>>>(out, gate_w, gate_b, g, gmax);
  gate_exp_kernel<<<cdiv(NN, B), B, 0, stream>>>(g, gmax, gsum);
  pool_kernel<<<512, 128, 0, stream>>>(out, g, gacc);
  finalize_kernel<<<1, 128, 0, stream>>>(gacc, gsum, out);
}

// Round 5
// 602.598 us; speedup vs baseline: 2.4084x; 2.4084x over previous
//
#include <hip/hip_runtime.h>

#define NN 60000
#define NE 300000

static inline int cdiv(int a, int b) { return (a + b - 1) / b; }

__device__ inline unsigned ord_enc(float x) {
  unsigned u = __float_as_uint(x);
  return (u & 0x80000000u) ? ~u : (u | 0x80000000u);
}
__device__ inline float ord_dec(unsigned u) {
  return __uint_as_float((u & 0x80000000u) ? (u & 0x7fffffffu) : ~u);
}

// ---------------- fold: precompute folded weight products (7424 dots of length 64) -------
__global__ void fold_kernel(const float* __restrict__ fp_w, const float* __restrict__ fp_b,
                            const float* __restrict__ ep_w, const float* __restrict__ ep_b,
                            const float* __restrict__ fij, const float* __restrict__ ebias,
                            const float* __restrict__ ni, const float* __restrict__ nj,
                            const float* __restrict__ node, float* __restrict__ fold) {
  int t = blockIdx.x * blockDim.x + threadIdx.x;
  if (t >= 7424) return;
  int o = t & 63;
  const float* A;
  const float* B;
  float init = 0.f;
  if (t < 1024)      { A = ep_w + (size_t)(t >> 6) * 64; B = fij + o; }
  else if (t < 1088) { A = ep_b; B = fij + o; init = ebias[o]; }
  else if (t < 3136) { A = fp_w + (size_t)((t - 1088) >> 6) * 64; B = ni + o; }
  else if (t < 5184) { A = fp_w + (size_t)((t - 3136) >> 6) * 64; B = nj + o; }
  else if (t < 7232) { A = fp_w + (size_t)((t - 5184) >> 6) * 64; B = node + o; }
  else if (t < 7296) { A = fp_b; B = ni + o; }
  else if (t < 7360) { A = fp_b; B = nj + o; }
  else               { A = fp_b; B = node + o; }
  float a = init;
  for (int i = 0; i < 64; ++i) a = fmaf(A[i], B[(size_t)i * 64], a);
  fold[t] = a;
}

// ---------------- tiled GEMM (rows x K) @ (K x 64): 3 weight sets via blockIdx.y ---------
// block = 256 threads, tile = 128 rows x 64 cols; thread computes 4 rows x 8 cols.
template <int K, bool BIAS>
__global__ __launch_bounds__(256, 2) void gemm3_kernel(
    const float* __restrict__ A, const float* __restrict__ W0, const float* __restrict__ W1,
    const float* __restrict__ W2, const float* __restrict__ b0, const float* __restrict__ b1,
    const float* __restrict__ b2, float* __restrict__ o0, float* __restrict__ o1,
    float* __restrict__ o2, int rows) {
  __shared__ float sA[128][K + 1];
  __shared__ float sW[K][64];
  const float* W = blockIdx.y == 0 ? W0 : blockIdx.y == 1 ? W1 : W2;
  const float* bb = blockIdx.y == 0 ? b0 : blockIdx.y == 1 ? b1 : b2;
  float* out = blockIdx.y == 0 ? o0 : blockIdx.y == 1 ? o1 : o2;
  int t = threadIdx.x;
  int r0 = blockIdx.x * 128;
  for (int i = t; i < K * 16; i += 256) ((float4*)sW)[i] = ((const float4*)W)[i];
  for (int i = t; i < 128 * (K / 4); i += 256) {
    int rr = i / (K / 4), cc = i % (K / 4);
    float4 v = (r0 + rr < rows) ? ((const float4*)(A + (size_t)(r0 + rr) * K))[cc]
                                : make_float4(0.f, 0.f, 0.f, 0.f);
    sA[rr][cc * 4 + 0] = v.x;
    sA[rr][cc * 4 + 1] = v.y;
    sA[rr][cc * 4 + 2] = v.z;
    sA[rr][cc * 4 + 3] = v.w;
  }
  __syncthreads();
  int rg = t >> 3, cg = t & 7;
  float acc[4][8];
#pragma unroll
  for (int i = 0; i < 4; ++i)
#pragma unroll
    for (int j = 0; j < 8; ++j) acc[i][j] = 0.f;
#pragma unroll 8
  for (int k = 0; k < K; ++k) {
    float a0 = sA[rg * 4 + 0][k], a1 = sA[rg * 4 + 1][k];
    float a2 = sA[rg * 4 + 2][k], a3 = sA[rg * 4 + 3][k];
    float4 wA = *(const float4*)&sW[k][cg * 8];
    float4 wB = *(const float4*)&sW[k][cg * 8 + 4];
    acc[0][0] = fmaf(a0, wA.x, acc[0][0]); acc[0][1] = fmaf(a0, wA.y, acc[0][1]);
    acc[0][2] = fmaf(a0, wA.z, acc[0][2]); acc[0][3] = fmaf(a0, wA.w, acc[0][3]);
    acc[0][4] = fmaf(a0, wB.x, acc[0][4]); acc[0][5] = fmaf(a0, wB.y, acc[0][5]);
    acc[0][6] = fmaf(a0, wB.z, acc[0][6]); acc[0][7] = fmaf(a0, wB.w, acc[0][7]);
    acc[1][0] = fmaf(a1, wA.x, acc[1][0]); acc[1][1] = fmaf(a1, wA.y, acc[1][1]);
    acc[1][2] = fmaf(a1, wA.z, acc[1][2]); acc[1][3] = fmaf(a1, wA.w, acc[1][3]);
    acc[1][4] = fmaf(a1, wB.x, acc[1][4]); acc[1][5] = fmaf(a1, wB.y, acc[1][5]);
    acc[1][6] = fmaf(a1, wB.z, acc[1][6]); acc[1][7] = fmaf(a1, wB.w, acc[1][7]);
    acc[2][0] = fmaf(a2, wA.x, acc[2][0]); acc[2][1] = fmaf(a2, wA.y, acc[2][1]);
    acc[2][2] = fmaf(a2, wA.z, acc[2][2]); acc[2][3] = fmaf(a2, wA.w, acc[2][3]);
    acc[2][4] = fmaf(a2, wB.x, acc[2][4]); acc[2][5] = fmaf(a2, wB.y, acc[2][5]);
    acc[2][6] = fmaf(a2, wB.z, acc[2][6]); acc[2][7] = fmaf(a2, wB.w, acc[2][7]);
    acc[3][0] = fmaf(a3, wA.x, acc[3][0]); acc[3][1] = fmaf(a3, wA.y, acc[3][1]);
    acc[3][2] = fmaf(a3, wA.z, acc[3][2]); acc[3][3] = fmaf(a3, wA.w, acc[3][3]);
    acc[3][4] = fmaf(a3, wB.x, acc[3][4]); acc[3][5] = fmaf(a3, wB.y, acc[3][5]);
    acc[3][6] = fmaf(a3, wB.z, acc[3][6]); acc[3][7] = fmaf(a3, wB.w, acc[3][7]);
  }
  float bv[8];
#pragma unroll
  for (int j = 0; j < 8; ++j) bv[j] = BIAS ? bb[cg * 8 + j] : 0.f;
#pragma unroll
  for (int i = 0; i < 4; ++i) {
    int r = r0 + rg * 4 + i;
    if (r < rows) {
      float4 v0 = make_float4(acc[i][0] + bv[0], acc[i][1] + bv[1], acc[i][2] + bv[2],
                              acc[i][3] + bv[3]);
      float4 v1 = make_float4(acc[i][4] + bv[4], acc[i][5] + bv[5], acc[i][6] + bv[6],
                              acc[i][7] + bv[7]);
      float4* op = (float4*)(out + (size_t)r * 64 + cg * 8);
      op[0] = v0;
      op[1] = v1;
    }
  }
}

// ---------------- edge GEMM + fused f_out epilogue + attention logit ----------------
// f_out[e][c] = leaky(A[e]@W[:,c] + hs[src[e]][c] + hd[dst[e]][c] + bias[c])
// logit[e] = sum_c f_out[e][c]*attn[c]; atomicMax per dst.
template <int K, bool STORE>
__global__ __launch_bounds__(256, 2) void gemm_fout_kernel(
    const float* __restrict__ A, const float* __restrict__ W, const float* __restrict__ bias,
    const float* __restrict__ hs, const float* __restrict__ hd, const int* __restrict__ src,
    const int* __restrict__ dst, const float* __restrict__ attn, float* __restrict__ fstore,
    float* __restrict__ logit, unsigned* __restrict__ nmax) {
  __shared__ float sA[128][K + 1];
  __shared__ float sW[K][64];
  int t = threadIdx.x;
  int r0 = blockIdx.x * 128;
  for (int i = t; i < K * 16; i += 256) ((float4*)sW)[i] = ((const float4*)W)[i];
  for (int i = t; i < 128 * (K / 4); i += 256) {
    int rr = i / (K / 4), cc = i % (K / 4);
    float4 v = (r0 + rr < NE) ? ((const float4*)(A + (size_t)(r0 + rr) * K))[cc]
                              : make_float4(0.f, 0.f, 0.f, 0.f);
    sA[rr][cc * 4 + 0] = v.x;
    sA[rr][cc * 4 + 1] = v.y;
    sA[rr][cc * 4 + 2] = v.z;
    sA[rr][cc * 4 + 3] = v.w;
  }
  __syncthreads();
  int rg = t >> 3, cg = t & 7;
  float acc[4][8];
#pragma unroll
  for (int i = 0; i < 4; ++i)
#pragma unroll
    for (int j = 0; j < 8; ++j) acc[i][j] = 0.f;
#pragma unroll 8
  for (int k = 0; k < K; ++k) {
    float a0 = sA[rg * 4 + 0][k], a1 = sA[rg * 4 + 1][k];
    float a2 = sA[rg * 4 + 2][k], a3 = sA[rg * 4 + 3][k];
    float4 wA = *(const float4*)&sW[k][cg * 8];
    float4 wB = *(const float4*)&sW[k][cg * 8 + 4];
    acc[0][0] = fmaf(a0, wA.x, acc[0][0]); acc[0][1] = fmaf(a0, wA.y, acc[0][1]);
    acc[0][2] = fmaf(a0, wA.z, acc[0][2]); acc[0][3] = fmaf(a0, wA.w, acc[0][3]);
    acc[0][4] = fmaf(a0, wB.x, acc[0][4]); acc[0][5] = fmaf(a0, wB.y, acc[0][5]);
    acc[0][6] = fmaf(a0, wB.z, acc[0][6]); acc[0][7] = fmaf(a0, wB.w, acc[0][7]);
    acc[1][0] = fmaf(a1, wA.x, acc[1][0]); acc[1][1] = fmaf(a1, wA.y, acc[1][1]);
    acc[1][2] = fmaf(a1, wA.z, acc[1][2]); acc[1][3] = fmaf(a1, wA.w, acc[1][3]);
    acc[1][4] = fmaf(a1, wB.x, acc[1][4]); acc[1][5] = fmaf(a1, wB.y, acc[1][5]);
    acc[1][6] = fmaf(a1, wB.z, acc[1][6]); acc[1][7] = fmaf(a1, wB.w, acc[1][7]);
    acc[2][0] = fmaf(a2, wA.x, acc[2][0]); acc[2][1] = fmaf(a2, wA.y, acc[2][1]);
    acc[2][2] = fmaf(a2, wA.z, acc[2][2]); acc[2][3] = fmaf(a2, wA.w, acc[2][3]);
    acc[2][4] = fmaf(a2, wB.x, acc[2][4]); acc[2][5] = fmaf(a2, wB.y, acc[2][5]);
    acc[2][6] = fmaf(a2, wB.z, acc[2][6]); acc[2][7] = fmaf(a2, wB.w, acc[2][7]);
    acc[3][0] = fmaf(a3, wA.x, acc[3][0]); acc[3][1] = fmaf(a3, wA.y, acc[3][1]);
    acc[3][2] = fmaf(a3, wA.z, acc[3][2]); acc[3][3] = fmaf(a3, wA.w, acc[3][3]);
    acc[3][4] = fmaf(a3, wB.x, acc[3][4]); acc[3][5] = fmaf(a3, wB.y, acc[3][5]);
    acc[3][6] = fmaf(a3, wB.z, acc[3][6]); acc[3][7] = fmaf(a3, wB.w, acc[3][7]);
  }
  float bv[8], av[8];
#pragma unroll
  for (int j = 0; j < 8; ++j) {
    bv[j] = bias[cg * 8 + j];
    av[j] = attn[cg * 8 + j];
  }
#pragma unroll
  for (int i = 0; i < 4; ++i) {
    int r = r0 + rg * 4 + i;
    if (r < NE) {
      int s = src[r], d = dst[r];
      const float4* hsp = (const float4*)(hs + (size_t)s * 64 + cg * 8);
      const float4* hdp = (const float4*)(hd + (size_t)d * 64 + cg * 8);
      float4 sa = hsp[0], sb = hsp[1], da = hdp[0], db = hdp[1];
      float fo[8];
      fo[0] = acc[i][0] + sa.x + da.x + bv[0];
      fo[1] = acc[i][1] + sa.y + da.y + bv[1];
      fo[2] = acc[i][2] + sa.z + da.z + bv[2];
      fo[3] = acc[i][3] + sa.w + da.w + bv[3];
      fo[4] = acc[i][4] + sb.x + db.x + bv[4];
      fo[5] = acc[i][5] + sb.y + db.y + bv[5];
      fo[6] = acc[i][6] + sb.z + db.z + bv[6];
      fo[7] = acc[i][7] + sb.w + db.w + bv[7];
      float p = 0.f;
#pragma unroll
      for (int j = 0; j < 8; ++j) {
        fo[j] = fo[j] >= 0.f ? fo[j] : 0.01f * fo[j];  // LeakyReLU
        p = fmaf(fo[j], av[j], p);
      }
      if (STORE) {
        float4* fp = (float4*)(fstore + (size_t)r * 64 + cg * 8);
        fp[0] = make_float4(fo[0], fo[1], fo[2], fo[3]);
        fp[1] = make_float4(fo[4], fo[5], fo[6], fo[7]);
      }
      // reduce p across the 8 col-group lanes (cg = low 3 bits of lane)
      p += __shfl_xor(p, 1, 64);
      p += __shfl_xor(p, 2, 64);
      p += __shfl_xor(p, 4, 64);
      if (cg == 0) {
        logit[r] = p;
        atomicMax(nmax + d, ord_enc(p));
      }
    }
  }
}

// ---------------- EGAT: edge softmax numerator + segment denom ----------------
__global__ void expsum_kernel(const float* __restrict__ logit, const int* __restrict__ dst,
                              const unsigned* __restrict__ nmax, float* __restrict__ wbuf,
                              float* __restrict__ nsum) {
  int e = blockIdx.x * blockDim.x + threadIdx.x;
  if (e >= NE) return;
  int d = dst[e];
  float m = ord_dec(nmax[d]);
  float w = __expf(logit[e] - m);
  wbuf[e] = w;
  atomicAdd(nsum + d, w);
}

// ---------------- EGAT: scatter-aggregate (softmax normalization fused) ----------------
__global__ void aggregate_kernel(const float* __restrict__ hn, const int* __restrict__ src,
                                 const int* __restrict__ dst, const float* __restrict__ wbuf,
                                 const float* __restrict__ nsum, float* __restrict__ hnew) {
  int idx = blockIdx.x * blockDim.x + threadIdx.x;
  if (idx >= NE * 64) return;
  int e = idx >> 6, o = idx & 63;
  int d = dst[e];
  float a = wbuf[e] / nsum[d];
  float v = hn[(size_t)src[e] * 64 + o] * a;
  atomicAdd(hnew + (size_t)d * 64 + o, v);
}

// ---------------- NNConv stage 1: per-node z = face @ nn_w, q = face @ nn_b --------------
#define ZCHUNK 128
__global__ void zq_kernel(const float* __restrict__ face, const float* __restrict__ nn_w,
                          const float* __restrict__ nn_b, float* __restrict__ z,
                          float* __restrict__ q) {
  __shared__ float s_x[ZCHUNK * 32];
  int tid = threadIdx.x;
  int c = blockIdx.y * 256 + tid;  // 0..767, active < 544
  float w[32];
  float* outp = z;
  int stride = 512;
  if (c < 512) {
    int o = c >> 4, k = c & 15;
#pragma unroll
    for (int i = 0; i < 32; ++i) w[i] = nn_w[(size_t)k * 1024 + i * 32 + o];
    outp = z + c;
  } else if (c < 544) {
    int o = c - 512;
#pragma unroll
    for (int i = 0; i < 32; ++i) w[i] = nn_b[(size_t)i * 32 + o];
    outp = q + o;
    stride = 32;
  }
  int nbase = blockIdx.x * ZCHUNK;
  int ncnt = min(ZCHUNK, NN - nbase);
  for (int j = tid; j < ncnt * 32; j += 256) s_x[j] = face[(size_t)nbase * 32 + j];
  __syncthreads();
  if (c >= 544) return;
  for (int nl = 0; nl < ncnt; ++nl) {
    const float4* xr = (const float4*)(s_x + nl * 32);
    float acc = 0.f;
#pragma unroll
    for (int j = 0; j < 8; ++j) {
      float4 xv = xr[j];
      acc = fmaf(xv.x, w[j * 4 + 0], acc);
      acc = fmaf(xv.y, w[j * 4 + 1], acc);
      acc = fmaf(xv.z, w[j * 4 + 2], acc);
      acc = fmaf(xv.w, w[j * 4 + 3], acc);
    }
    outp[(size_t)(nbase + nl) * stride] = acc;
  }
}

// ---------------- NNConv stage 2: per-edge m[e][o] = q[s][o] + sum_k ef[e][k]*z[s][o*16+k]
__global__ void nnconv_edge_kernel(const float* __restrict__ z, const float* __restrict__ q,
                                   const float* __restrict__ ef, const int* __restrict__ src,
                                   const int* __restrict__ dst, float* __restrict__ sArr,
                                   float* __restrict__ cnt) {
  int gid = blockIdx.x * blockDim.x + threadIdx.x;
  if (gid >= NE * 32) return;
  int e = gid >> 5, o = gid & 31;
  int s = src[e], d = dst[e];
  const float4* zr = (const float4*)(z + (size_t)s * 512 + o * 16);
  const float4* er = (const float4*)(ef + (size_t)e * 16);
  float acc = q[(size_t)s * 32 + o];
#pragma unroll
  for (int j = 0; j < 4; ++j) {
    float4 zv = zr[j], ev = er[j];
    acc = fmaf(ev.x, zv.x, acc);
    acc = fmaf(ev.y, zv.y, acc);
    acc = fmaf(ev.z, zv.z, acc);
    acc = fmaf(ev.w, zv.w, acc);
  }
  atomicAdd(sArr + (size_t)d * 32 + o, acc);
  if (o == 0) atomicAdd(cnt + d, 1.0f);
}

// ---------------- combine into node_features ----------------
__global__ void combine_kernel(const float* __restrict__ hfin, const float* __restrict__ sArr,
                               const float* __restrict__ cnt, const float* __restrict__ nn_bias,
                               float* __restrict__ out) {
  int idx = blockIdx.x * blockDim.x + threadIdx.x;
  if (idx >= NN * 128) return;
  int n = idx >> 7, c = idx & 127;
  float v;
  if (c < 64) v = hfin[(size_t)n * 64 + c];
  else if (c < 96) v = sArr[(size_t)n * 32 + (c - 64)] / fmaxf(cnt[n], 1.0f) + nn_bias[c - 64];
  else v = 0.f;
  out[idx] = v;
}

// ---------------- global attention pooling ----------------
__global__ void gate_logit_kernel(const float* __restrict__ nf, const float* __restrict__ gate_w,
                                  const float* __restrict__ gate_b, float* __restrict__ g,
                                  unsigned* __restrict__ gmax) {
  int n = blockIdx.x * blockDim.x + threadIdx.x;
  float v = -3.0e38f;
  if (n < NN) {
    float acc = gate_b[0];
    const float* r = nf + (size_t)n * 128;
#pragma unroll
    for (int c = 0; c < 96; ++c) acc = fmaf(r[c], gate_w[c], acc);  // cols 96..127 are zero
    g[n] = acc;
    v = acc;
  }
#pragma unroll
  for (int off = 32; off; off >>= 1) v = fmaxf(v, __shfl_xor(v, off, 64));
  __shared__ float sm[4];
  int lane = threadIdx.x & 63, wid = threadIdx.x >> 6;
  if (lane == 0) sm[wid] = v;
  __syncthreads();
  if (threadIdx.x == 0) {
    float m = fmaxf(fmaxf(sm[0], sm[1]), fmaxf(sm[2], sm[3]));
    atomicMax(gmax, ord_enc(m));
  }
}

__global__ void gate_exp_kernel(float* __restrict__ g, const unsigned* __restrict__ gmax,
                                float* __restrict__ gsum) {
  int n = blockIdx.x * blockDim.x + threadIdx.x;
  float m = ord_dec(*gmax);
  float w = 0.f;
  if (n < NN) { w = __expf(g[n] - m); g[n] = w; }
  float v = w;
#pragma unroll
  for (int off = 32; off; off >>= 1) v += __shfl_xor(v, off, 64);
  __shared__ float sm[4];
  int lane = threadIdx.x & 63, wid = threadIdx.x >> 6;
  if (lane == 0) sm[wid] = v;
  __syncthreads();
  if (threadIdx.x == 0) atomicAdd(gsum, sm[0] + sm[1] + sm[2] + sm[3]);
}

__global__ void pool_kernel(const float* __restrict__ nf, const float* __restrict__ gw,
                            float* __restrict__ gacc) {
  int o = threadIdx.x;  // blockDim = 128
  float acc = 0.f;
  for (int n = blockIdx.x; n < NN; n += gridDim.x)
    acc += gw[n] * nf[(size_t)n * 128 + o];
  atomicAdd(gacc + o, acc);
}

__global__ void finalize_kernel(const float* __restrict__ gacc, const float* __restrict__ gsum,
                                float* __restrict__ out) {
  int o = threadIdx.x;
  if (o < 128) out[(size_t)NN * 128 + o] = gacc[o] / gsum[0];
}

extern "C" void kernel_launch(void* const* d_in, const int* in_sizes, int n_in,
                              void* d_out, int out_size, void* d_ws, size_t ws_size,
                              hipStream_t stream) {
  const float* face    = (const float*)d_in[0];
  const float* ef      = (const float*)d_in[1];
  const float* fp_w    = (const float*)d_in[2];
  const float* fp_b    = (const float*)d_in[3];
  const float* ep_w    = (const float*)d_in[4];
  const float* ep_b    = (const float*)d_in[5];
  const float* nn_w    = (const float*)d_in[6];
  const float* nn_b    = (const float*)d_in[7];
  const float* nn_bias = (const float*)d_in[8];
  const float* gate_w  = (const float*)d_in[9];
  const float* gate_b  = (const float*)d_in[10];
  const int*   src     = (const int*)d_in[11];
  const int*   dst     = (const int*)d_in[12];
  const float* e1_attn = (const float*)d_in[17];
  const float* e2_ni   = (const float*)d_in[19];
  const float* e2_nj   = (const float*)d_in[20];
  const float* e2_fij  = (const float*)d_in[21];
  const float* e2_node = (const float*)d_in[22];
  const float* e2_attn = (const float*)d_in[23];
  const float* e2_bias = (const float*)d_in[24];
  float* out = (float*)d_out;

  char* p = (char*)d_ws;
  auto alloc = [&](size_t nfloats) {
    float* r = (float*)p;
    p += ((nfloats * 4 + 255) / 256) * 256;
    return r;
  };
  float* h0 = alloc((size_t)NN * 64);   // layer-2 output
  float* h1 = alloc((size_t)NN * 64);   // layer-1 output; q aliases after EGAT
  char* regionC = p;                    // hs|hd|hn|f1 = 122.88 MB, dead after EGAT
  float* hs    = alloc((size_t)NN * 64);
  float* hd    = alloc((size_t)NN * 64);
  float* hn    = alloc((size_t)NN * 64);
  float* f1    = alloc((size_t)NE * 64);
  float* logit = alloc(NE);
  float* wbuf  = alloc(NE);
  unsigned* nmax = (unsigned*)alloc(NN);
  float* nsum  = alloc(NN);
  float* sArr  = alloc((size_t)NN * 32);
  float* cnt   = alloc(NN);
  float* g     = alloc(NN);
  float* gacc  = alloc(128);
  float* gsum  = alloc(1);
  unsigned* gmax = (unsigned*)alloc(1);
  float* fold  = alloc(7424);
  float* z = (float*)regionC;           // NN*512 floats == hs+hd+hn+f1 region
  float* q = h1;                        // NN*32 <= h1's NN*64, h1 dead post-EGAT

  const float* Wf1  = fold;
  const float* b1f  = fold + 1024;
  const float* Wni1 = fold + 1088;
  const float* Wnj1 = fold + 3136;
  const float* Wno1 = fold + 5184;
  const float* bni1 = fold + 7232;
  const float* bnj1 = fold + 7296;
  const float* bno1 = fold + 7360;

  const int B = 256;
  const int NGB = cdiv(NN, 128);   // node GEMM blocks
  const int EGB = cdiv(NE, 128);   // edge GEMM blocks

  // folded weights (tiny)
  fold_kernel<<<29, B, 0, stream>>>(fp_w, fp_b, ep_w, ep_b,
                                    (const float*)d_in[15], (const float*)d_in[18],
                                    (const float*)d_in[13], (const float*)d_in[14],
                                    (const float*)d_in[16], fold);

  // ---- EGAT layer 1 (face-level folds: h0/f0 never materialized) ----
  hipMemsetAsync(nmax, 0, NN * 4, stream);
  hipMemsetAsync(nsum, 0, NN * 4, stream);
  hipMemsetAsync(h1, 0, (size_t)NN * 64 * 4, stream);
  gemm3_kernel<32, true><<<dim3(NGB, 3), B, 0, stream>>>(face, Wni1, Wnj1, Wno1, bni1, bnj1,
                                                         bno1, hs, hd, hn, NN);
  gemm_fout_kernel<16, true><<<EGB, B, 0, stream>>>(ef, Wf1, b1f, hs, hd, src, dst, e1_attn,
                                                    f1, logit, nmax);
  expsum_kernel<<<cdiv(NE, B), B, 0, stream>>>(logit, dst, nmax, wbuf, nsum);
  aggregate_kernel<<<cdiv(NE * 64, B), B, 0, stream>>>(hn, src, dst, wbuf, nsum, h1);

  // ---- EGAT layer 2 ----
  hipMemsetAsync(nmax, 0, NN * 4, stream);
  hipMemsetAsync(nsum, 0, NN * 4, stream);
  hipMemsetAsync(h0, 0, (size_t)NN * 64 * 4, stream);
  gemm3_kernel<64, false><<<dim3(NGB, 3), B, 0, stream>>>(h1, e2_ni, e2_nj, e2_node, nullptr,
                                                          nullptr, nullptr, hs, hd, hn, NN);
  gemm_fout_kernel<64, false><<<EGB, B, 0, stream>>>(f1, e2_fij, e2_bias, hs, hd, src, dst,
                                                     e2_attn, nullptr, logit, nmax);
  expsum_kernel<<<cdiv(NE, B), B, 0, stream>>>(logit, dst, nmax, wbuf, nsum);
  aggregate_kernel<<<cdiv(NE * 64, B), B, 0, stream>>>(hn, src, dst, wbuf, nsum, h0);

  // ---- NNConv (z/q alias dead EGAT buffers — must run after EGAT) ----
  hipMemsetAsync(sArr, 0, (size_t)NN * 32 * 4, stream);
  hipMemsetAsync(cnt, 0, NN * 4, stream);
  {
    dim3 zg(cdiv(NN, ZCHUNK), 3);
    zq_kernel<<<zg, B, 0, stream>>>(face, nn_w, nn_b, z, q);
  }
  nnconv_edge_kernel<<<cdiv(NE * 32, B), B, 0, stream>>>(z, q, ef, src, dst, sArr, cnt);

  // ---- combine node features (Gf | Ef | zeros) ----
  combine_kernel<<<cdiv(NN * 128, B), B, 0, stream>>>(h0, sArr, cnt, nn_bias, out);

  // ---- global attention pooling ----
  hipMemsetAsync(gacc, 0, 128 * 4, stream);
  hipMemsetAsync(gsum, 0, 4, stream);
  hipMemsetAsync(gmax, 0, 4, stream);
  gate_logit_kernel<<<cdiv(NN, B), B, 0, stream>>>(out, gate_w, gate_b, g, gmax);
  gate_exp_kernel<<<cdiv(NN, B), B, 0, stream>>>(g, gmax, gsum);
  pool_kernel<<<512, 128, 0, stream>>>(out, g, gacc);
  finalize_kernel<<<1, 128, 0, stream>>>(gacc, gsum, out);
}